// Round 16
// baseline (290.986 us; speedup 1.0000x reference)
//
#include <hip/hip_runtime.h>
#include <cstdint>
#include <cmath>

#define BATCH 65536
#define NREAL 246
#define NPAD  256
#define K1    784
#define K1PAD 832
#define BINS  100
#define ALPHA 0.1f
#define RB    32
#define NBLK  (BATCH/RB)     // 2048

typedef __bf16 bf16x8 __attribute__((ext_vector_type(8)));
typedef __bf16 bf16x4 __attribute__((ext_vector_type(4)));
typedef float  f32x4  __attribute__((ext_vector_type(4)));

// LDS layout (bytes)
#define OFF_HS     0         // Hs[2]: 2 * 32 rows * 512B = 32768
#define OFF_STAGE  32768     // L1 stage dbuf 2*4096 (union with hist)
#define OFF_HIST   32768     // 8 waves * 400 bins * 4B = 12800
#define OFF_MN     45568     // [2][32 rows][8 waves] f32 = 2048
#define OFF_MX     47616     // 2048
#define OFF_WENT   49664     // 8 waves * 6 layers * 4B = 192
#define LDS_TOTAL  49856     // 48.7 KB -> 3 blocks/CU

// ---------------- weight/bias pad/convert ----------------
__global__ __launch_bounds__(256)
void pad_weights(const float* __restrict__ W1, const float* __restrict__ W2,
                 const float* __restrict__ W3, const float* __restrict__ W4,
                 const float* __restrict__ W5, const float* __restrict__ W6,
                 const float* __restrict__ W7,
                 const float* __restrict__ b1, const float* __restrict__ b2,
                 const float* __restrict__ b3, const float* __restrict__ b4,
                 const float* __restrict__ b5, const float* __restrict__ b6,
                 __bf16* __restrict__ W1p, __bf16* __restrict__ Wp,
                 __bf16* __restrict__ W7p, float* __restrict__ bpad)
{
    int tid = blockIdx.x * 256 + threadIdx.x;
    const int n1 = NPAD * K1PAD;        // 212992
    const int n2 = 5 * NPAD * NPAD;     // 327680
    const int n3 = 16 * NPAD;           // 4096
    if (tid < n1) {
        int row = tid / K1PAD;
        int k   = tid - row * K1PAD;
        W1p[tid] = (__bf16)((row < NREAL && k < K1) ? W1[row * K1 + k] : 0.0f);
    } else if (tid < n1 + n2) {
        int t = tid - n1;
        int wsel = t >> 16;
        int idx  = t & 65535;
        int row  = idx >> 8, k = idx & 255;
        const float* W = (wsel == 0) ? W2 : (wsel == 1) ? W3 : (wsel == 2) ? W4
                        : (wsel == 3) ? W5 : W6;
        Wp[t] = (__bf16)((row < NREAL && k < NREAL) ? W[row * NREAL + k] : 0.0f);
    } else if (tid < n1 + n2 + n3) {
        int t = tid - n1 - n2;
        int row = t >> 8, k = t & 255;
        W7p[t] = (__bf16)((row < 10 && k < NREAL) ? W7[row * NREAL + k] : 0.0f);
    } else if (tid < n1 + n2 + n3 + 6 * NPAD) {
        int t = tid - n1 - n2 - n3;
        int li = t >> 8, k = t & 255;
        const float* b = (li == 0) ? b1 : (li == 1) ? b2 : (li == 2) ? b3
                        : (li == 3) ? b4 : (li == 4) ? b5 : b6;
        bpad[t] = (k < NREAL) ? b[k] : 0.0f;
    }
}

// ---------------- megakernel: 8 waves x (32r x 32c), Hs dbuf, 1 barrier/layer ----------------
__global__ __launch_bounds__(512)
void mega(const float* __restrict__ x,
          const __bf16* __restrict__ W1p,
          const __bf16* __restrict__ Wp,
          const __bf16* __restrict__ W7p,
          const float* __restrict__ bpad,
          const float* __restrict__ b7,
          float* __restrict__ out, float* __restrict__ partial)
{
    __shared__ char smem[LDS_TOTAL];
    char*  Hball = smem + OFF_HS;
    float* rowmn = (float*)(smem + OFF_MN);   // [buf][row*8+w]
    float* rowmx = (float*)(smem + OFF_MX);
    float* went  = (float*)(smem + OFF_WENT);

    const int tid = threadIdx.x;
    const int w = tid >> 6, l = tid & 63;
    const int lane16 = l & 15, lane4 = l >> 4;
    const int wc = w * 32;               // wave's 32-col strip
    const int m0 = blockIdx.x * RB;

    // entropy mapping: wave-private rows w*4..w*4+3, 16 lanes per row
    const int rg = l >> 4, q = l & 15;
    const int erow = w * 4 + rg;
    const int eswz = (erow & 7) << 4;
    int* histW = (int*)(smem + OFF_HIST) + w * 400;

    f32x4 acc[2][2];
#pragma unroll
    for (int i = 0; i < 2; ++i)
#pragma unroll
        for (int j = 0; j < 2; ++j) acc[i][j] = f32x4{0.f, 0.f, 0.f, 0.f};

    bf16x8 Bq[2][2];     // 2-slot ring x 2 col-frags = 16 VGPRs

    auto loadBq = [&](int s, const __bf16* Bbase, int hh) {
        const __bf16* pp = Bbase + (size_t)(wc + lane16) * NPAD + hh * 32 + lane4 * 8;
#pragma unroll
        for (int j = 0; j < 2; ++j)
            Bq[s][j] = *(const bf16x8*)(pp + (size_t)j * 16 * NPAD);
    };

    auto zeroHist = [&]() {
        int4* hz = (int4*)histW;
        const int4 z = int4{0, 0, 0, 0};
        hz[l] = z;
        if (l < 36) hz[64 + l] = z;
    };

    // pure-GEMM layer: 8 phases, no DS ops besides af reads -> pipelines cleanly
    auto gemmLayer = [&](const char* Hs_, const __bf16* WpP, const __bf16* WpN) {
#pragma unroll
        for (int i = 0; i < 2; ++i)
#pragma unroll
            for (int j = 0; j < 2; ++j) acc[i][j] = f32x4{0.f, 0.f, 0.f, 0.f};
        const int sw0 = (lane16 & 7) << 4;
#pragma unroll
        for (int h = 0; h < 8; ++h) {
            bf16x8 af0 = *(const bf16x8*)(Hs_ + (lane16) * 512      + ((h * 64 + lane4 * 16) ^ sw0));
            bf16x8 af1 = *(const bf16x8*)(Hs_ + (16 + lane16) * 512 + ((h * 64 + lane4 * 16) ^ sw0));
            __builtin_amdgcn_s_setprio(1);
            acc[0][0] = __builtin_amdgcn_mfma_f32_16x16x32_bf16((h & 1) ? Bq[1][0] : Bq[0][0], af0, acc[0][0], 0, 0, 0);
            acc[0][1] = __builtin_amdgcn_mfma_f32_16x16x32_bf16((h & 1) ? Bq[1][1] : Bq[0][1], af0, acc[0][1], 0, 0, 0);
            acc[1][0] = __builtin_amdgcn_mfma_f32_16x16x32_bf16((h & 1) ? Bq[1][0] : Bq[0][0], af1, acc[1][0], 0, 0, 0);
            acc[1][1] = __builtin_amdgcn_mfma_f32_16x16x32_bf16((h & 1) ? Bq[1][1] : Bq[0][1], af1, acc[1][1], 0, 0, 0);
            __builtin_amdgcn_s_setprio(0);
            if (h < 6)           loadBq(h & 1, WpP, h + 2);
            else if (WpN != nullptr) loadBq(h & 1, WpN, h - 6);   // bootstrap next layer
        }
    };

    // entropy burst: 2 b128 reads + 16 fire-and-forget atomics; NO reads-after-atomics here
    auto entropyBurst = [&](const char* Hs_, int sbuf) {
        f32x4 a0 = *(const f32x4*)(rowmn + sbuf * 256 + erow * 8);
        f32x4 a1 = *(const f32x4*)(rowmn + sbuf * 256 + erow * 8 + 4);
        f32x4 b0 = *(const f32x4*)(rowmx + sbuf * 256 + erow * 8);
        f32x4 b1 = *(const f32x4*)(rowmx + sbuf * 256 + erow * 8 + 4);
        f32x4 mnv = __builtin_elementwise_min(a0, a1);
        f32x4 mxv = __builtin_elementwise_max(b0, b1);
        float emn = fminf(fminf(mnv[0], mnv[1]), fminf(mnv[2], mnv[3]));
        float emx = fmaxf(fmaxf(mxv[0], mxv[1]), fmaxf(mxv[2], mxv[3]));
        float ers = (emx > emn) ? 100.0f / (emx - emn) : 0.0f;
        float eb  = -emn * ers;
        bf16x8 h0 = *(const bf16x8*)(Hs_ + erow * 512 + ((q * 32) ^ eswz));
        bf16x8 h1 = *(const bf16x8*)(Hs_ + erow * 512 + ((q * 32 + 16) ^ eswz));
        int* hrow = histW + rg * 100;
#pragma unroll
        for (int e = 0; e < 8; ++e) {
            int c = q * 16 + e;
            if (c < NREAL) {
                int idx = (int)fmaf((float)h0[e], ers, eb);
                idx = idx > BINS - 1 ? BINS - 1 : (idx < 0 ? 0 : idx);
                atomicAdd(&hrow[idx], 1);
            }
        }
#pragma unroll
        for (int e = 0; e < 8; ++e) {
            int c = q * 16 + 8 + e;
            if (c < NREAL) {
                int idx = (int)fmaf((float)h1[e], ers, eb);
                idx = idx > BINS - 1 ? BINS - 1 : (idx < 0 ? 0 : idx);
                atomicAdd(&hrow[idx], 1);
            }
        }
    };

    // bias + leaky (packed f32), write Hs[dst] + rowmn/mx[dbuf]
    auto epilogue = [&](f32x4 bq0, f32x4 bq1, char* Hd, int dbuf) {
        const f32x4 zero = f32x4{0.f, 0.f, 0.f, 0.f};
#pragma unroll
        for (int i = 0; i < 2; ++i) {
            const int m = i * 16 + lane16;
            const int swz = (m & 7) << 4;
            f32x4 mn4 = f32x4{1e30f, 1e30f, 1e30f, 1e30f};
            f32x4 mx4 = f32x4{-1e30f, -1e30f, -1e30f, -1e30f};
#pragma unroll
            for (int j = 0; j < 2; ++j) {
                const int nbase = wc + j * 16 + lane4 * 4;
                f32x4 v = acc[i][j] + (j ? bq1 : bq0);
                f32x4 lk = __builtin_elementwise_max(v, zero)
                         + ALPHA * __builtin_elementwise_min(v, zero);
                bf16x4 hv;
                if (nbase + 4 <= NREAL) {
#pragma unroll
                    for (int r = 0; r < 4; ++r) hv[r] = (__bf16)lk[r];
                    mn4 = __builtin_elementwise_min(mn4, lk);
                    mx4 = __builtin_elementwise_max(mx4, lk);
                } else {
#pragma unroll
                    for (int r = 0; r < 4; ++r) {
                        bool valid = (nbase + r) < NREAL;
                        hv[r] = valid ? (__bf16)lk[r] : (__bf16)0.0f;
                        mn4[r] = fminf(mn4[r], valid ? lk[r] : 1e30f);
                        mx4[r] = fmaxf(mx4[r], valid ? lk[r] : -1e30f);
                    }
                }
                *(bf16x4*)(Hd + m * 512 + ((nbase * 2) ^ swz)) = hv;
            }
            float mn = fminf(fminf(mn4[0], mn4[1]), fminf(mn4[2], mn4[3]));
            float mx = fmaxf(fmaxf(mx4[0], mx4[1]), fmaxf(mx4[2], mx4[3]));
            mn = fminf(mn, __shfl_xor(mn, 16, 64));
            mx = fmaxf(mx, __shfl_xor(mx, 16, 64));
            mn = fminf(mn, __shfl_xor(mn, 32, 64));
            mx = fmaxf(mx, __shfl_xor(mx, 32, 64));
            if (lane4 == 0) {
                rowmn[dbuf * 256 + m * 8 + w] = mn;
                rowmx[dbuf * 256 + m * 8 + w] = mx;
            }
        }
    };

    auto esum = [&](int li) {
        const int* hrow = histW + rg * 100;
        float S = 0.0f;
#pragma unroll
        for (int t = 0; t < 7; ++t) {
            int b = q * 7 + t;
            if (b < 100) {
                float f = (float)hrow[b];
                float g = fmaxf(f, 1.0f);
                S = fmaf(f, __logf(g), S);
            }
        }
#pragma unroll
        for (int off = 1; off < 64; off <<= 1) S += __shfl_xor(S, off, 64);
        if (l == 0) went[w * 6 + li] = 4.0f * logf(246.0f) - S * (1.0f / 246.0f);
    };

    // ================= layer 1: K=784 streamed from HBM via reg-relay stage =================
    {
        const int srow = tid >> 4;        // 0..31
        const int skc  = (tid & 15) * 4;  // k offset within 64
        float4 xr;
        auto issueX = [&](int kt) {
            int k0 = kt * 64 + skc;
            if (k0 < K1) {
                xr = *(const float4*)(x + (size_t)(m0 + srow) * K1 + k0);
            } else {
                xr = float4{0.f, 0.f, 0.f, 0.f};
            }
        };
        auto writeX = [&](int buf) {
            bf16x4 h;
            h[0]=(__bf16)xr.x; h[1]=(__bf16)xr.y; h[2]=(__bf16)xr.z; h[3]=(__bf16)xr.w;
            char* st = smem + OFF_STAGE + buf * 4096;
            *(bf16x4*)(st + srow * 128 + ((skc * 2) ^ ((srow & 7) << 4))) = h;
        };
        auto lB = [&](int s, int kt, int kk) {
            const __bf16* p = W1p + (size_t)(wc + lane16) * K1PAD + kt * 64 + kk * 32 + lane4 * 8;
#pragma unroll
            for (int j = 0; j < 2; ++j)
                Bq[s][j] = *(const bf16x8*)(p + (size_t)j * 16 * K1PAD);
        };
        auto cH = [&](const char* st, int kbyte, int s) {
#pragma unroll
            for (int i = 0; i < 2; ++i) {
                int m = i * 16 + lane16;
                bf16x8 af = *(const bf16x8*)(st + m * 128 + ((kbyte + lane4 * 16) ^ ((m & 7) << 4)));
                __builtin_amdgcn_s_setprio(1);
#pragma unroll
                for (int j = 0; j < 2; ++j)
                    acc[i][j] = __builtin_amdgcn_mfma_f32_16x16x32_bf16(s ? Bq[1][j] : Bq[0][j], af, acc[i][j], 0, 0, 0);
                __builtin_amdgcn_s_setprio(0);
            }
        };

        issueX(0); writeX(0); issueX(1);
        lB(0, 0, 0);
        for (int kt = 0; kt < 13; ++kt) {
            __syncthreads();
            if (kt < 12) { writeX((kt + 1) & 1); if (kt < 11) issueX(kt + 2); }
            const char* st = smem + OFF_STAGE + (kt & 1) * 4096;
            lB(1, kt, 1);
            cH(st, 0, 0);
            if (kt < 12) lB(0, kt + 1, 0);
            cH(st, 64, 1);
        }
    }

    // L1 tail: bootstrap layer-2 Bq + bias, write Hs[0]
    loadBq(0, Wp, 0);
    loadBq(1, Wp, 1);
    {
        f32x4 bq0 = *(const f32x4*)(bpad + wc + lane4 * 4);
        f32x4 bq1 = *(const f32x4*)(bpad + wc + 16 + lane4 * 4);
        epilogue(bq0, bq1, Hball, 0);
    }
    __syncthreads();            // Hs[0]+minmax[0] visible; L1 stage dead -> hist usable
    zeroHist();                 // wave-private; in-order DS vs own later atomics

    // ================= layers 2..6: 1 barrier per layer =================
    for (int p = 0; p < 5; ++p) {
        const char* Hs_ = Hball + (p & 1) * 16384;
        char*       Hd  = Hball + ((p & 1) ^ 1) * 16384;
        const __bf16* WpP = Wp + (size_t)p * (NPAD * NPAD);

        gemmLayer(Hs_, WpP, (p < 4) ? WpP + NPAD * NPAD : nullptr);
        // hoist bias loads (L2) so they fly under the entropy burst
        f32x4 bq0 = *(const f32x4*)(bpad + (size_t)(p + 1) * NPAD + wc + lane4 * 4);
        f32x4 bq1 = *(const f32x4*)(bpad + (size_t)(p + 1) * NPAD + wc + 16 + lane4 * 4);
        entropyBurst(Hs_, p & 1);               // fire-and-forget atomics
        epilogue(bq0, bq1, Hd, (p & 1) ^ 1);    // VALU-heavy; atomics drain underneath
        asm volatile("s_waitcnt lgkmcnt(0)" ::: "memory");   // own atomics done
        esum(p);
        zeroHist();                              // in-order DS after esum reads
        __syncthreads();                         // Hs[next]+minmax[next] visible
    }

    // ================= tail: entropy(Hs[1] = layer-6 acts) =================
    entropyBurst(Hball + 16384, 1);
    asm volatile("s_waitcnt lgkmcnt(0)" ::: "memory");
    esum(5);

    // ================= head: waves 0..1, one 16-row MFMA strip each =================
    if (w < 2) {
        const char* H6 = Hball + 16384;
        f32x4 hacc = f32x4{0.f, 0.f, 0.f, 0.f};
        int row = w * 16 + lane16;
#pragma unroll
        for (int kt = 0; kt < 8; ++kt) {
            bf16x8 af = *(const bf16x8*)(H6 + row * 512 + ((kt * 64 + lane4 * 16) ^ ((row & 7) << 4)));
            bf16x8 bf = *(const bf16x8*)(W7p + (size_t)lane16 * NPAD + kt * 32 + lane4 * 8);
            hacc = __builtin_amdgcn_mfma_f32_16x16x32_bf16(af, bf, hacc, 0, 0, 0);
        }
        float bv = (lane16 < 10) ? b7[lane16] : 0.0f;
#pragma unroll
        for (int r = 0; r < 4; ++r) {
            float lg = fmaxf(hacc[r] + bv, 0.0f);
            float vm = (lane16 < 10) ? lg : -1e30f;
#pragma unroll
            for (int off = 8; off; off >>= 1) vm = fmaxf(vm, __shfl_xor(vm, off, 64));
            float ex = (lane16 < 10) ? expf(lg - vm) : 0.0f;
#pragma unroll
            for (int off = 8; off; off >>= 1) ex += __shfl_xor(ex, off, 64);
            float ls = vm + logf(ex);
            if (lane16 < 10) {
                int grow = m0 + w * 16 + lane4 * 4 + r;
                out[(size_t)grow * 10 + lane16] = lg - ls;
            }
        }
    }

    __syncthreads();
    if (tid < 6) {
        float s = 0.0f;
#pragma unroll
        for (int qq = 0; qq < 8; ++qq) s += went[qq * 6 + tid];
        partial[tid * NBLK + blockIdx.x] = s;
    }
}

// ---------------- final entropy mean (deterministic fixed-order) ----------------
__global__ __launch_bounds__(256)
void reduce_kernel(const float* __restrict__ partial, float* __restrict__ out)
{
    __shared__ float s[256];
    const int li = blockIdx.x, tid = threadIdx.x;
    float a = 0.0f;
    for (int i = tid; i < NBLK; i += 256) a += partial[li * NBLK + i];
    s[tid] = a;
    __syncthreads();
    for (int st = 128; st; st >>= 1) {
        if (tid < st) s[tid] += s[tid + st];
        __syncthreads();
    }
    if (tid == 0)
        out[(size_t)BATCH * 10 + li] = s[0] / (float)BATCH + logf((float)BINS);
}

// ---------------- launch ----------------
extern "C" void kernel_launch(void* const* d_in, const int* in_sizes, int n_in,
                              void* d_out, int out_size, void* d_ws, size_t ws_size,
                              hipStream_t stream)
{
    (void)in_sizes; (void)n_in; (void)out_size; (void)ws_size;

    const float* x  = (const float*)d_in[0];
    const float* W1 = (const float*)d_in[1];
    const float* b1 = (const float*)d_in[2];
    const float* W2 = (const float*)d_in[3];
    const float* b2 = (const float*)d_in[4];
    const float* W3 = (const float*)d_in[5];
    const float* b3 = (const float*)d_in[6];
    const float* W4 = (const float*)d_in[7];
    const float* b4 = (const float*)d_in[8];
    const float* W5 = (const float*)d_in[9];
    const float* b5 = (const float*)d_in[10];
    const float* W6 = (const float*)d_in[11];
    const float* b6 = (const float*)d_in[12];
    const float* W7 = (const float*)d_in[13];
    const float* b7 = (const float*)d_in[14];

    char* ws = (char*)d_ws;
    // ws layout (bytes):
    //   0       : W1p  256*832 bf16   = 425984
    //   425984  : Wp   5*256*256 bf16 = 655360
    //   1081344 : W7p  16*256 bf16    = 8192
    //   1089536 : bpad 6*256 f32      = 6144
    //   1095680 : partial 6*2048 f32  = 49152
    __bf16* W1p = (__bf16*)(ws);
    __bf16* Wp  = (__bf16*)(ws + 425984);
    __bf16* W7p = (__bf16*)(ws + 1081344);
    float*  bpad = (float*)(ws + 1089536);
    float*  partial = (float*)(ws + 1095680);
    float*  out = (float*)d_out;

    pad_weights<<<2134, 256, 0, stream>>>(W1, W2, W3, W4, W5, W6, W7,
                                          b1, b2, b3, b4, b5, b6,
                                          W1p, Wp, W7p, bpad);
    mega<<<NBLK, 512, 0, stream>>>(x, W1p, Wp, W7p, bpad, b7, out, partial);
    reduce_kernel<<<6, 256, 0, stream>>>(partial, out);
}